// Round 5
// baseline (376.183 us; speedup 1.0000x reference)
//
#include <hip/hip_runtime.h>
#include <hip/hip_bf16.h>
#include <math.h>

typedef __bf16 bf16_t;
typedef __bf16 bf16x8 __attribute__((ext_vector_type(8)));
typedef __bf16 bf16x4 __attribute__((ext_vector_type(4)));
typedef float  f32x4  __attribute__((ext_vector_type(4)));

// Problem geometry (fixed): x[4][2048][1024], w1[1024][4096], w2[4096][1024]
#define NROWS 8192   // 4*2048
#define HD    1024
#define DFF   4096
#define HKEEP 544    // h-columns materialized (Hermitian: only h<=512 independent)

typedef __attribute__((address_space(1))) const void* gas_cptr;
typedef __attribute__((address_space(3))) void* las_ptr;

__device__ __forceinline__ void gload_lds16(const void* g, void* l) {
  __builtin_amdgcn_global_load_lds((gas_cptr)g, (las_ptr)l, 16, 0, 0);
}

// ---------------- transpose + f32->bf16 convert (w1 -> [DFF][H], w2 -> [H][DFF])
__global__ __launch_bounds__(256) void transpose_to_bf16(
    const float* __restrict__ in, bf16_t* __restrict__ out, int R, int C)
{
  __shared__ float tile[32][33];
  const int bx = blockIdx.x, by = blockIdx.y;
  const int tx = threadIdx.x, ty = threadIdx.y;
  #pragma unroll
  for (int i = ty; i < 32; i += 8)
    tile[i][tx] = in[(size_t)(by*32 + i)*C + bx*32 + tx];
  __syncthreads();
  #pragma unroll
  for (int i = ty; i < 32; i += 8)
    out[(size_t)(bx*32 + i)*R + by*32 + tx] = (bf16_t)tile[tx][i];
}

// ---------------- 1024-pt FFT along h, one row per block, real input.
__global__ __launch_bounds__(256) void fft_h_kernel(
    const float* __restrict__ x, float* __restrict__ re, float* __restrict__ im)
{
  __shared__ float sre[1024], sim[1024], twc[512], tws[512];
  const int t = threadIdx.x;
  const size_t row = blockIdx.x;
  const float* xr = x + row * HD;
  for (int k = t; k < 512; k += 256) {
    float sv, cv; sincosf(-6.28318530717958647692f * (float)k * (1.0f/1024.0f), &sv, &cv);
    twc[k] = cv; tws[k] = sv;
  }
  #pragma unroll
  for (int q = 0; q < 4; ++q) sre[t + 256*q] = xr[t + 256*q];
  __syncthreads();
  float rv[4];
  #pragma unroll
  for (int q = 0; q < 4; ++q) rv[q] = sre[__brev((unsigned)(t + 256*q)) >> 22];
  __syncthreads();
  #pragma unroll
  for (int q = 0; q < 4; ++q) { sre[t + 256*q] = rv[q]; sim[t + 256*q] = 0.0f; }
  __syncthreads();
  for (int s = 0; s < 10; ++s) {
    const int half = 1 << s;
    #pragma unroll
    for (int q = 0; q < 2; ++q) {
      const int b  = t + 256*q;
      const int j  = b & (half - 1);
      const int ib = ((b >> s) << (s + 1)) | j;
      const int ti2 = j << (9 - s);
      const float wc = twc[ti2], ws = tws[ti2];
      const float r1 = sre[ib],       i1v = sim[ib];
      const float r2 = sre[ib+half],  i2v = sim[ib+half];
      const float tr = r2*wc - i2v*ws;
      const float ti = r2*ws + i2v*wc;
      sre[ib]      = r1 + tr; sim[ib]      = i1v + ti;
      sre[ib+half] = r1 - tr; sim[ib+half] = i1v - ti;
    }
    __syncthreads();
  }
  #pragma unroll
  for (int q = 0; q < 4; ++q) {
    const int idx = t + 256*q;
    if (idx < HKEEP) {
      re[row*HD + idx] = sre[idx];
      im[row*HD + idx] = sim[idx];
    }
  }
}

// ---------------- tiled transpose of re,im: [8192][1024] -> [HKEEP][8192]
__global__ __launch_bounds__(256) void transpose2_f32(
    const float* __restrict__ re, const float* __restrict__ im,
    float* __restrict__ reT, float* __restrict__ imT)
{
  __shared__ float t0[32][33], t1[32][33];
  const int h0 = blockIdx.x * 32;   // < HKEEP
  const int b0 = blockIdx.y * 32;
  const int tx = threadIdx.x, ty = threadIdx.y;
  #pragma unroll
  for (int i = ty; i < 32; i += 8) {
    t0[i][tx] = re[(size_t)(b0+i)*HD + h0+tx];
    t1[i][tx] = im[(size_t)(b0+i)*HD + h0+tx];
  }
  __syncthreads();
  #pragma unroll
  for (int i = ty; i < 32; i += 8) {
    reT[(size_t)(h0+i)*NROWS + b0+tx] = t0[tx][i];
    imT[(size_t)(h0+i)*NROWS + b0+tx] = t1[tx][i];
  }
}

// ---------------- 2048-pt FFT along s, one (h, batch) column per block.
__global__ __launch_bounds__(256) void fft_s_col(
    const float* __restrict__ reT, const float* __restrict__ imT,
    float* __restrict__ fT)
{
  __shared__ float sre[2048], sim[2048], twc[1024], tws[1024];
  const int t = threadIdx.x;
  const int h = blockIdx.x;           // 0..512
  const int batch = blockIdx.y;       // 0..3
  const size_t base = (size_t)h * NROWS + batch * 2048;
  for (int k = t; k < 1024; k += 256) {
    float sv, cv; sincosf(-6.28318530717958647692f * (float)k * (1.0f/2048.0f), &sv, &cv);
    twc[k] = cv; tws[k] = sv;
  }
  #pragma unroll
  for (int q = 0; q < 8; ++q) {
    const int i = t + 256*q;
    const int src = __brev((unsigned)i) >> 21;   // 11-bit bit reversal
    sre[i] = reT[base + src];
    sim[i] = imT[base + src];
  }
  __syncthreads();
  for (int s = 0; s < 11; ++s) {
    const int half = 1 << s;
    #pragma unroll
    for (int q = 0; q < 4; ++q) {
      const int b  = t + 256*q;
      const int j  = b & (half - 1);
      const int ib = ((b >> s) << (s + 1)) | j;
      const int ti2 = j << (10 - s);
      const float wc = twc[ti2], ws = tws[ti2];
      const float r1 = sre[ib],       i1v = sim[ib];
      const float r2 = sre[ib+half],  i2v = sim[ib+half];
      const float tr = r2*wc - i2v*ws;
      const float ti = r2*ws + i2v*wc;
      sre[ib]      = r1 + tr; sim[ib]      = i1v + ti;
      sre[ib+half] = r1 - tr; sim[ib+half] = i1v - ti;
    }
    __syncthreads();
  }
  #pragma unroll
  for (int q = 0; q < 8; ++q) {
    const int i = t + 256*q;
    fT[base + i] = sre[i];
  }
}

// ---------------- untranspose + Hermitian mirror + residual add
__global__ __launch_bounds__(256) void umadd_kernel(
    const float* __restrict__ fT, const float* __restrict__ x,
    float* __restrict__ y)
{
  __shared__ float tile[32][33];
  const int h0 = blockIdx.x * 32;
  const int b0 = blockIdx.y * 32;
  const int tx = threadIdx.x, ty = threadIdx.y;
  const int batch = b0 >> 11;
  const int s0    = b0 & 2047;
  #pragma unroll
  for (int i = ty; i < 32; i += 8) {
    const int h = h0 + i;
    float v;
    if (h <= 512) {
      v = fT[(size_t)h * NROWS + b0 + tx];
    } else {
      const int sp = (2048 - (s0 + tx)) & 2047;
      v = fT[(size_t)(1024 - h) * NROWS + (batch << 11) + sp];
    }
    tile[i][tx] = v;
  }
  __syncthreads();
  #pragma unroll
  for (int i = ty; i < 32; i += 8) {
    const size_t gi = (size_t)(b0+i)*HD + h0+tx;
    y[gi] = x[gi] + tile[tx][i];
  }
}

// ---------------- LayerNorm over H=1024, one row per block (256 thr x 4 elems)
template <bool OUT_BF16>
__global__ __launch_bounds__(256) void layernorm_k(
    const float* __restrict__ in, const float* __restrict__ gw,
    const float* __restrict__ gb, bf16_t* __restrict__ ob, float* __restrict__ of)
{
  __shared__ float red[8];
  const size_t row = blockIdx.x;
  const int t = threadIdx.x;
  const float* xr = in + row * HD;
  float4 v = *(const float4*)(xr + t*4);
  float s = v.x + v.y + v.z + v.w;
  #pragma unroll
  for (int o = 32; o > 0; o >>= 1) s += __shfl_xor(s, o);
  if ((t & 63) == 0) red[t >> 6] = s;
  __syncthreads();
  const float mu = (red[0]+red[1]+red[2]+red[3]) * (1.0f/1024.0f);
  const float dx = v.x-mu, dy = v.y-mu, dz = v.z-mu, dw = v.w-mu;
  float sq = dx*dx + dy*dy + dz*dz + dw*dw;
  #pragma unroll
  for (int o = 32; o > 0; o >>= 1) sq += __shfl_xor(sq, o);
  if ((t & 63) == 0) red[4 + (t >> 6)] = sq;
  __syncthreads();
  const float var  = (red[4]+red[5]+red[6]+red[7]) * (1.0f/1024.0f);
  const float rstd = rsqrtf(var + 1e-5f);
  const float4 wv = *(const float4*)(gw + t*4);
  const float4 bv = *(const float4*)(gb + t*4);
  const float o0 = dx*rstd*wv.x + bv.x;
  const float o1 = dy*rstd*wv.y + bv.y;
  const float o2 = dz*rstd*wv.z + bv.z;
  const float o3 = dw*rstd*wv.w + bv.w;
  if constexpr (OUT_BF16) {
    bf16x4 o; o[0]=(bf16_t)o0; o[1]=(bf16_t)o1; o[2]=(bf16_t)o2; o[3]=(bf16_t)o3;
    *(bf16x4*)(ob + row*HD + t*4) = o;
  } else {
    float4 o; o.x=o0; o.y=o1; o.z=o2; o.w=o3;
    *(float4*)(of + row*HD + t*4) = o;
  }
}

__device__ __forceinline__ float gelu_exact(float v) {
  return 0.5f * v * (1.0f + erff(v * 0.70710678118654752440f));
}

// ---------------- 8-phase 256xBN bf16 MFMA GEMM (T2+T3+T4+T5)
// BM=256, BK=64, 8 waves (2Mx4N), per-wave 128 x (NFRAG*16).
// Double-buffered LDS; 2 K-tiles per iteration; 8 phases each:
//   {ds_read frags | stage 1 half-tile unit} -> barrier -> lgkmcnt(0) ->
//   setprio(1) -> MFMA quadrant -> setprio(0) -> [counted vmcnt] -> barrier
// Stage slot schedule (unit free-time proven):
//   ph1: B1(t1)->b1  ph2: A0(t1)->b1  ph3: A1(t1)->b1  ph4: B0(t2)->b0
//   ph5: B1(t2)->b0  ph6: A0(t2)->b0  ph7: A1(t2)->b0  ph8: B0(t3)->b1
// Counted waits only at end-ph4 / end-ph8 (vmcnt = loads of newest slot).
template <int NFRAG, bool GELU_OUT>
__global__ __launch_bounds__(512, 2) void gemm8_kernel(
    const bf16_t* __restrict__ A,     // [M][K]
    const bf16_t* __restrict__ Bt,    // [N][K]
    const float*  __restrict__ bias,  // [N]
    const bf16_t* __restrict__ resid, // [M][N] (only when !GELU_OUT)
    bf16_t* __restrict__ outB, float* __restrict__ outF,
    int M, int N, int K, int gx)
{
  constexpr int BN = NFRAG * 64;
  constexpr int BH = BN / 2;                 // B half-tile rows
  __shared__ bf16_t As[2][256 * 64];
  __shared__ bf16_t Bs[2][BN * 64];

  const int tid  = threadIdx.x;
  const int wave = tid >> 6, lane = tid & 63;
  const int wr = wave >> 2, wc = wave & 3;   // 2x4 waves
  const int lr = lane & 15, lkg = lane >> 4;

  const int nwg = gridDim.x;
  const int sid = (blockIdx.x & 7) * (nwg >> 3) + (blockIdx.x >> 3);
  const int bx = sid % gx, by = sid / gx;
  const int brow = by * 256, bcol = bx * BN;

  // staging lane decomposition (8 rows x 8 k-groups per wave-instruction)
  const int rl = lane >> 3;
  const int sg = (lane & 7) ^ rl;            // pre-swizzled source k-group
  const bf16_t* Abase = A  + (size_t)(brow + wave*8 + rl) * K + sg*8;
  const bf16_t* Bbase = Bt + (size_t)(bcol + wave*8 + rl) * K + sg*8;

  auto stageA = [&](int b, int h, int t) {
    const bf16_t* g = Abase + (size_t)(h*128) * K + t*64;
    bf16_t* l = &As[b][(h*128 + wave*8) * 64];
    gload_lds16(g, l);
    gload_lds16(g + (size_t)64 * K, l + 64*64);
  };
  auto stageB = [&](int b, int h, int t) {
    const bf16_t* g = Bbase + (size_t)(h*BH) * K + t*64;
    bf16_t* l = &Bs[b][(h*BH + wave*8) * 64];
    gload_lds16(g, l);
    if constexpr (NFRAG == 4)
      gload_lds16(g + (size_t)64 * K, l + 64*64);
  };

  f32x4 acc[8][NFRAG] = {};
  bf16x8 af[4], bv[NFRAG];

  const int NT = K >> 6;       // K-tiles
  const int NI = NT >> 1;      // iterations (2 tiles each)

  // prologue: tiles 0 and 1 fully staged, drained once
  stageA(0,0,0); stageA(0,1,0); stageB(0,0,0); stageB(0,1,0);
  stageA(1,0,1); stageA(1,1,1); stageB(1,0,1); stageB(1,1,1);
  asm volatile("s_waitcnt vmcnt(0)" ::: "memory");
  __builtin_amdgcn_s_barrier();

  #define RD_B(BUF, KS) _Pragma("unroll") \
      for (int n = 0; n < NFRAG; ++n) { \
        const int r = wc*(NFRAG*16) + n*16 + lr; \
        bv[n] = *(const bf16x8*)&Bs[BUF][r*64 + (((lkg + KS*4) ^ (lr & 7))*8)]; }
  #define RD_A(BUF, MH, KS) _Pragma("unroll") \
      for (int m = 0; m < 4; ++m) { \
        const int r = wr*128 + (MH*4 + m)*16 + lr; \
        af[m] = *(const bf16x8*)&As[BUF][r*64 + (((lkg + KS*4) ^ (lr & 7))*8)]; }
  #define MFMA_Q(MH) __builtin_amdgcn_s_setprio(1); \
      _Pragma("unroll") \
      for (int m = 0; m < 4; ++m) { \
        _Pragma("unroll") \
        for (int n = 0; n < NFRAG; ++n) \
          acc[MH*4 + m][n] = __builtin_amdgcn_mfma_f32_16x16x32_bf16(bv[n], af[m], acc[MH*4 + m][n], 0, 0, 0); } \
      __builtin_amdgcn_s_setprio(0);
  #define BAR() __builtin_amdgcn_s_barrier()
  #define LGKM0() asm volatile("s_waitcnt lgkmcnt(0)" ::: "memory")
  #define VMW() do { if constexpr (NFRAG == 4) asm volatile("s_waitcnt vmcnt(2)" ::: "memory"); \
                     else                      asm volatile("s_waitcnt vmcnt(1)" ::: "memory"); } while(0)

  for (int j = 0; j < NI; ++j) {
    const int t1 = 2*j + 1;
    const int t2 = (2*j + 2 < NT) ? 2*j + 2 : NT - 1;
    const int t3 = (2*j + 3 < NT) ? 2*j + 3 : NT - 1;

    // ph1: buf0 (mh0,ks0) + bv ks0 | stage B1(t1)->b1
    RD_B(0,0); RD_A(0,0,0); stageB(1,1,t1);
    BAR(); LGKM0(); MFMA_Q(0); BAR();
    // ph2: buf0 (mh1,ks0) | stage A0(t1)->b1
    RD_A(0,1,0); stageA(1,0,t1);
    BAR(); LGKM0(); MFMA_Q(1); BAR();
    // ph3: buf0 (mh0,ks1) + bv ks1 | stage A1(t1)->b1
    RD_B(0,1); RD_A(0,0,1); stageA(1,1,t1);
    BAR(); LGKM0(); MFMA_Q(0); BAR();
    // ph4: buf0 (mh1,ks1) | stage B0(t2)->b0 | wait
    RD_A(0,1,1); stageB(0,0,t2);
    BAR(); LGKM0(); MFMA_Q(1); VMW(); BAR();
    // ph5: buf1 (mh0,ks0) + bv ks0 | stage B1(t2)->b0
    RD_B(1,0); RD_A(1,0,0); stageB(0,1,t2);
    BAR(); LGKM0(); MFMA_Q(0); BAR();
    // ph6: buf1 (mh1,ks0) | stage A0(t2)->b0
    RD_A(1,1,0); stageA(0,0,t2);
    BAR(); LGKM0(); MFMA_Q(1); BAR();
    // ph7: buf1 (mh0,ks1) + bv ks1 | stage A1(t2)->b0
    RD_B(1,1); RD_A(1,0,1); stageA(0,1,t2);
    BAR(); LGKM0(); MFMA_Q(0); BAR();
    // ph8: buf1 (mh1,ks1) | stage B0(t3)->b1 | wait
    RD_A(1,1,1); stageB(1,0,t3);
    BAR(); LGKM0(); MFMA_Q(1); VMW(); BAR();
  }

  // epilogue: acc[m][n][j] = C[wr*128+m*16+lr][wc*(NFRAG*16)+n*16+lkg*4+j]
  #pragma unroll
  for (int m = 0; m < 8; ++m) {
    const int row = brow + wr*128 + m*16 + lr;
    #pragma unroll
    for (int n = 0; n < NFRAG; ++n) {
      const int col = bcol + wc*(NFRAG*16) + n*16 + lkg*4;
      const float4 bv4 = *(const float4*)(bias + col);
      float v0 = acc[m][n][0] + bv4.x;
      float v1 = acc[m][n][1] + bv4.y;
      float v2 = acc[m][n][2] + bv4.z;
      float v3 = acc[m][n][3] + bv4.w;
      if constexpr (GELU_OUT) {
        bf16x4 o;
        o[0] = (bf16_t)gelu_exact(v0); o[1] = (bf16_t)gelu_exact(v1);
        o[2] = (bf16_t)gelu_exact(v2); o[3] = (bf16_t)gelu_exact(v3);
        *(bf16x4*)(outB + (size_t)row * N + col) = o;
      } else {
        bf16x4 rr = *(const bf16x4*)(resid + (size_t)row * N + col);
        float4 o;
        o.x = v0 + (float)rr[0]; o.y = v1 + (float)rr[1];
        o.z = v2 + (float)rr[2]; o.w = v3 + (float)rr[3];
        *(float4*)(outF + (size_t)row * N + col) = o;
      }
    }
  }
  #undef RD_B
  #undef RD_A
  #undef MFMA_Q
  #undef BAR
  #undef LGKM0
  #undef VMW
}

extern "C" void kernel_launch(void* const* d_in, const int* in_sizes, int n_in,
                              void* d_out, int out_size, void* d_ws, size_t ws_size,
                              hipStream_t stream) {
  const float* x    = (const float*)d_in[0];
  const float* ln1w = (const float*)d_in[1];
  const float* ln1b = (const float*)d_in[2];
  const float* ln2w = (const float*)d_in[3];
  const float* ln2b = (const float*)d_in[4];
  const float* w1   = (const float*)d_in[5];
  const float* b1   = (const float*)d_in[6];
  const float* w2   = (const float*)d_in[7];
  const float* b2   = (const float*)d_in[8];
  float* out = (float*)d_out;

  char* ws = (char*)d_ws;
  bf16_t* w1b = (bf16_t*)(ws);
  bf16_t* w2b = (bf16_t*)(ws + (8u  << 20));
  float*  re  = (float*) (ws + (16u << 20));
  float*  im  = (float*) (ws + (48u << 20));
  float*  reT = (float*) (ws + (80u << 20));
  float*  imT = (float*) (ws + (98u << 20));
  float*  fT  = (float*) (ws + (16u << 20));
  float*  y   = (float*) (ws + (33u << 20));
  bf16_t* xn  = (bf16_t*)(ws + (16u << 20));
  bf16_t* hg  = (bf16_t*)(ws + (64u << 20));

  // 1. weight transposes + bf16 conversion
  transpose_to_bf16<<<dim3(DFF/32, HD/32), dim3(32, 8), 0, stream>>>(w1, w1b, HD, DFF);
  transpose_to_bf16<<<dim3(HD/32, DFF/32), dim3(32, 8), 0, stream>>>(w2, w2b, DFF, HD);

  // 2. FFT along h (writes h < HKEEP only)
  fft_h_kernel<<<NROWS, 256, 0, stream>>>(x, re, im);

  // 3. transpose re/im to [h][bs]
  transpose2_f32<<<dim3(HKEEP/32, NROWS/32), dim3(32, 8), 0, stream>>>(re, im, reT, imT);

  // 4. FFT along s per (h<=512, batch) column; real part out
  fft_s_col<<<dim3(513, 4), 256, 0, stream>>>(reT, imT, fT);

  // 5. untranspose + Hermitian mirror + residual add
  umadd_kernel<<<dim3(HD/32, NROWS/32), dim3(32, 8), 0, stream>>>(fT, x, y);

  // 6. LN1 -> bf16
  layernorm_k<true><<<NROWS, 256, 0, stream>>>(y, ln1w, ln1b, xn, nullptr);

  // 7./8. FFN: 8-phase 256-tile GEMMs (XCD-swizzled 1D grids)
  gemm8_kernel<4, true><<<(DFF/256)*(NROWS/256), 512, 0, stream>>>(
      xn, w1b, b1, nullptr, hg, nullptr, NROWS, DFF, HD, DFF/256);
  gemm8_kernel<2, false><<<(HD/128)*(NROWS/256), 512, 0, stream>>>(
      hg, w2b, b2, xn, nullptr, out, NROWS, HD, DFF, HD/128);

  // 9. LN2 in place on d_out
  layernorm_k<false><<<NROWS, 256, 0, stream>>>(out, ln2w, ln2b, nullptr, out);
}

// Round 6
// 326.903 us; speedup vs baseline: 1.1507x; 1.1507x over previous
//
#include <hip/hip_runtime.h>
#include <hip/hip_bf16.h>
#include <math.h>

typedef __bf16 bf16_t;
typedef __bf16 bf16x8 __attribute__((ext_vector_type(8)));
typedef __bf16 bf16x4 __attribute__((ext_vector_type(4)));
typedef float  f32x4  __attribute__((ext_vector_type(4)));

// Problem geometry (fixed): x[4][2048][1024], w1[1024][4096], w2[4096][1024]
#define NROWS 8192   // 4*2048
#define HD    1024
#define DFF   4096
#define HKEEP 513    // h-columns materialized (Hermitian: only h<=512 independent)

typedef __attribute__((address_space(1))) const void* gas_cptr;
typedef __attribute__((address_space(3))) void* las_ptr;

__device__ __forceinline__ void gload_lds16(const void* g, void* l) {
  __builtin_amdgcn_global_load_lds((gas_cptr)g, (las_ptr)l, 16, 0, 0);
}

// ---------------- transpose + f32->bf16 convert (w1 -> [DFF][H], w2 -> [H][DFF])
__global__ __launch_bounds__(256) void transpose_to_bf16(
    const float* __restrict__ in, bf16_t* __restrict__ out, int R, int C)
{
  __shared__ float tile[32][33];
  const int bx = blockIdx.x, by = blockIdx.y;
  const int tx = threadIdx.x, ty = threadIdx.y;
  #pragma unroll
  for (int i = ty; i < 32; i += 8)
    tile[i][tx] = in[(size_t)(by*32 + i)*C + bx*32 + tx];
  __syncthreads();
  #pragma unroll
  for (int i = ty; i < 32; i += 8)
    out[(size_t)(bx*32 + i)*R + by*32 + tx] = (bf16_t)tile[tx][i];
}

// ---------------- fused: 1024-pt FFT along h for 16 rows/block, real input,
// writes truncated spectrum (h < HKEEP) TRANSPOSED: reT/imT[h][row].
#define RPB 16
#define LDW 1036   // padded row stride (f32): 16B-aligned, col reads 2-way max
__global__ __launch_bounds__(512) void fft_h_t(
    const float* __restrict__ x, float* __restrict__ reT, float* __restrict__ imT)
{
  __shared__ float sre[RPB*LDW], sim[RPB*LDW], twc[512], tws[512];
  const int t = threadIdx.x;
  const int row0 = blockIdx.x * RPB;
  {
    float sv, cv; sincosf(-6.28318530717958647692f * (float)t * (1.0f/1024.0f), &sv, &cv);
    twc[t] = cv; tws[t] = sv;   // t in [0,512)
  }
  // load 16 rows, float4, linear
  #pragma unroll
  for (int q = 0; q < 8; ++q) {
    const int i = t + 512*q;            // 0..4095
    const int row = i >> 8, c4 = i & 255;
    float4 v = *(const float4*)(x + (size_t)(row0+row)*HD + c4*4);
    *(float4*)&sre[row*LDW + c4*4] = v;
  }
  __syncthreads();
  // in-LDS bit-reversal permute (+ zero imag)
  const int b0i = __brev((unsigned)t) >> 22;
  const int b1i = __brev((unsigned)(t + 512)) >> 22;
  float rv[32];
  #pragma unroll
  for (int q = 0; q < 16; ++q) {
    rv[2*q]   = sre[q*LDW + b0i];
    rv[2*q+1] = sre[q*LDW + b1i];
  }
  __syncthreads();
  #pragma unroll
  for (int q = 0; q < 16; ++q) {
    sre[q*LDW + t]       = rv[2*q];
    sre[q*LDW + t + 512] = rv[2*q+1];
    sim[q*LDW + t]       = 0.0f;
    sim[q*LDW + t + 512] = 0.0f;
  }
  __syncthreads();
  for (int s = 0; s < 10; ++s) {
    const int half = 1 << s;
    const int j    = t & (half - 1);
    const int ib   = ((t >> s) << (s + 1)) | j;
    const int ti2  = j << (9 - s);
    const float wc = twc[ti2], ws = tws[ti2];
    #pragma unroll
    for (int q = 0; q < 16; ++q) {
      float* pr = &sre[q*LDW]; float* pi = &sim[q*LDW];
      const float r1 = pr[ib],      i1v = pi[ib];
      const float r2 = pr[ib+half], i2v = pi[ib+half];
      const float tr = r2*wc - i2v*ws;
      const float ti = r2*ws + i2v*wc;
      pr[ib]      = r1 + tr; pi[ib]      = i1v + ti;
      pr[ib+half] = r1 - tr; pi[ib+half] = i1v - ti;
    }
    __syncthreads();
  }
  // truncated transposed store: thread (tx=row, th=h%32)
  const int tx = t & 15, th = t >> 4;    // th 0..31
  #pragma unroll
  for (int hh = 0; hh < 17; ++hh) {
    const int h = hh*32 + th;
    if (h < HKEEP) {
      reT[(size_t)h*NROWS + row0 + tx] = sre[tx*LDW + h];
      imT[(size_t)h*NROWS + row0 + tx] = sim[tx*LDW + h];
    }
  }
}

// ---------------- 2048-pt FFT along s, one (h, batch) column per block.
__global__ __launch_bounds__(256) void fft_s_col(
    const float* __restrict__ reT, const float* __restrict__ imT,
    float* __restrict__ fT)
{
  __shared__ float sre[2048], sim[2048], twc[1024], tws[1024];
  const int t = threadIdx.x;
  const int h = blockIdx.x;           // 0..512
  const int batch = blockIdx.y;       // 0..3
  const size_t base = (size_t)h * NROWS + batch * 2048;
  for (int k = t; k < 1024; k += 256) {
    float sv, cv; sincosf(-6.28318530717958647692f * (float)k * (1.0f/2048.0f), &sv, &cv);
    twc[k] = cv; tws[k] = sv;
  }
  #pragma unroll
  for (int q = 0; q < 8; ++q) {
    const int i = t + 256*q;
    const int src = __brev((unsigned)i) >> 21;   // 11-bit bit reversal
    sre[i] = reT[base + src];
    sim[i] = imT[base + src];
  }
  __syncthreads();
  for (int s = 0; s < 11; ++s) {
    const int half = 1 << s;
    #pragma unroll
    for (int q = 0; q < 4; ++q) {
      const int b  = t + 256*q;
      const int j  = b & (half - 1);
      const int ib = ((b >> s) << (s + 1)) | j;
      const int ti2 = j << (10 - s);
      const float wc = twc[ti2], ws = tws[ti2];
      const float r1 = sre[ib],       i1v = sim[ib];
      const float r2 = sre[ib+half],  i2v = sim[ib+half];
      const float tr = r2*wc - i2v*ws;
      const float ti = r2*ws + i2v*wc;
      sre[ib]      = r1 + tr; sim[ib]      = i1v + ti;
      sre[ib+half] = r1 - tr; sim[ib+half] = i1v - ti;
    }
    __syncthreads();
  }
  #pragma unroll
  for (int q = 0; q < 8; ++q) {
    const int i = t + 256*q;
    fT[base + i] = sre[i];
  }
}

// ---------------- untranspose + Hermitian mirror + residual add
__global__ __launch_bounds__(256) void umadd_kernel(
    const float* __restrict__ fT, const float* __restrict__ x,
    float* __restrict__ y)
{
  __shared__ float tile[32][33];
  const int h0 = blockIdx.x * 32;
  const int b0 = blockIdx.y * 32;
  const int tx = threadIdx.x, ty = threadIdx.y;
  const int batch = b0 >> 11;
  const int s0    = b0 & 2047;
  #pragma unroll
  for (int i = ty; i < 32; i += 8) {
    const int h = h0 + i;
    float v;
    if (h <= 512) {
      v = fT[(size_t)h * NROWS + b0 + tx];
    } else {
      const int sp = (2048 - (s0 + tx)) & 2047;
      v = fT[(size_t)(1024 - h) * NROWS + (batch << 11) + sp];
    }
    tile[i][tx] = v;
  }
  __syncthreads();
  #pragma unroll
  for (int i = ty; i < 32; i += 8) {
    const size_t gi = (size_t)(b0+i)*HD + h0+tx;
    y[gi] = x[gi] + tile[tx][i];
  }
}

// ---------------- LayerNorm over H=1024, one row per block (256 thr x 4 elems)
template <bool OUT_BF16>
__global__ __launch_bounds__(256) void layernorm_k(
    const float* __restrict__ in, const float* __restrict__ gw,
    const float* __restrict__ gb, bf16_t* __restrict__ ob, float* __restrict__ of)
{
  __shared__ float red[8];
  const size_t row = blockIdx.x;
  const int t = threadIdx.x;
  const float* xr = in + row * HD;
  float4 v = *(const float4*)(xr + t*4);
  float s = v.x + v.y + v.z + v.w;
  #pragma unroll
  for (int o = 32; o > 0; o >>= 1) s += __shfl_xor(s, o);
  if ((t & 63) == 0) red[t >> 6] = s;
  __syncthreads();
  const float mu = (red[0]+red[1]+red[2]+red[3]) * (1.0f/1024.0f);
  const float dx = v.x-mu, dy = v.y-mu, dz = v.z-mu, dw = v.w-mu;
  float sq = dx*dx + dy*dy + dz*dz + dw*dw;
  #pragma unroll
  for (int o = 32; o > 0; o >>= 1) sq += __shfl_xor(sq, o);
  if ((t & 63) == 0) red[4 + (t >> 6)] = sq;
  __syncthreads();
  const float var  = (red[4]+red[5]+red[6]+red[7]) * (1.0f/1024.0f);
  const float rstd = rsqrtf(var + 1e-5f);
  const float4 wv = *(const float4*)(gw + t*4);
  const float4 bv = *(const float4*)(gb + t*4);
  const float o0 = dx*rstd*wv.x + bv.x;
  const float o1 = dy*rstd*wv.y + bv.y;
  const float o2 = dz*rstd*wv.z + bv.z;
  const float o3 = dw*rstd*wv.w + bv.w;
  if constexpr (OUT_BF16) {
    bf16x4 o; o[0]=(bf16_t)o0; o[1]=(bf16_t)o1; o[2]=(bf16_t)o2; o[3]=(bf16_t)o3;
    *(bf16x4*)(ob + row*HD + t*4) = o;
  } else {
    float4 o; o.x=o0; o.y=o1; o.z=o2; o.w=o3;
    *(float4*)(of + row*HD + t*4) = o;
  }
}

// fast exact-enough GELU: tanh form via exp2; |err| vs erf-GELU ~1e-3 << 0.1075
__device__ __forceinline__ float gelu_fast(float v) {
  const float u  = 0.7978845608028654f * v * (1.0f + 0.044715f * v * v);
  const float e  = exp2f(-2.8853900817779268f * u);   // exp(-2u)
  return v / (1.0f + e);                               // v * sigmoid(2u)
}

// ---------------- bf16 MFMA GEMM: C = A[M][K] * Bt[N][K]^T (+bias, epilogue)
// 2-phase 128x128 tile, BK=64, 4 waves, global_load_lds width=16 staging,
// involution XOR k-group swizzle, swapped-operand MFMA (vectorized epilogue).
template <bool GELU_BF16_OUT>
__global__ __launch_bounds__(256) void gemm_bf16_kernel(
    const bf16_t* __restrict__ A,     // [M][K]
    const bf16_t* __restrict__ Bt,    // [N][K]  (= B^T, rows are output cols)
    const float*  __restrict__ bias,  // [N]
    const bf16_t* __restrict__ resid, // [M][N]  (only used when !GELU_BF16_OUT)
    bf16_t* __restrict__ outB, float* __restrict__ outF,
    int M, int N, int K, int gx)
{
  constexpr int BK = 64;
  __shared__ bf16_t As[128*BK];
  __shared__ bf16_t Bs[128*BK];
  const int tid  = threadIdx.x;
  const int wave = tid >> 6, lane = tid & 63;
  const int wr = wave >> 1, wc = wave & 1;     // 2x2 waves of 64x64
  const int lr  = lane & 15;
  const int lkg = lane >> 4;                   // k-group 0..3 (8 bf16 each)

  // XCD-aware bijective swizzle (grid % 8 == 0 for both GEMMs)
  const int nwg = gridDim.x;
  const int sid = (blockIdx.x & 7) * (nwg >> 3) + (blockIdx.x >> 3);
  const int bx = sid % gx, by = sid / gx;
  const int brow = by * 128, bcol = bx * 128;

  const int rloc = lane >> 3;                  // row within 8-row chunk
  const int sgrp = (lane & 7) ^ rloc;          // pre-swizzled source k-group
  const bf16_t* Ag = A  + (size_t)(brow + wave*32 + rloc) * K + sgrp * 8;
  const bf16_t* Bg = Bt + (size_t)(bcol + wave*32 + rloc) * K + sgrp * 8;

  f32x4 acc[4][4] = {};

  for (int k0 = 0; k0 < K; k0 += BK) {
    #pragma unroll
    for (int q = 0; q < 4; ++q) {
      gload_lds16(Ag + (size_t)(q*8)*K + k0, &As[(wave*4 + q) * 512]);
      gload_lds16(Bg + (size_t)(q*8)*K + k0, &Bs[(wave*4 + q) * 512]);
    }
    __syncthreads();

    #pragma unroll
    for (int ks = 0; ks < 2; ++ks) {
      const int g = (lkg + ks*4) ^ (lr & 7);   // swizzled k-group on read
      bf16x8 af[4], bv[4];
      #pragma unroll
      for (int m = 0; m < 4; ++m)
        af[m] = *(const bf16x8*)&As[(wr*64 + m*16 + lr)*BK + g*8];
      #pragma unroll
      for (int n = 0; n < 4; ++n)
        bv[n] = *(const bf16x8*)&Bs[(wc*64 + n*16 + lr)*BK + g*8];
      #pragma unroll
      for (int m = 0; m < 4; ++m)
        #pragma unroll
        for (int n = 0; n < 4; ++n)
          acc[m][n] = __builtin_amdgcn_mfma_f32_16x16x32_bf16(bv[n], af[m], acc[m][n], 0, 0, 0);
    }
    __syncthreads();
  }

  #pragma unroll
  for (int m = 0; m < 4; ++m) {
    const int row = brow + wr*64 + m*16 + lr;
    #pragma unroll
    for (int n = 0; n < 4; ++n) {
      const int col = bcol + wc*64 + n*16 + lkg*4;
      const float4 bv4 = *(const float4*)(bias + col);
      float v0 = acc[m][n][0] + bv4.x;
      float v1 = acc[m][n][1] + bv4.y;
      float v2 = acc[m][n][2] + bv4.z;
      float v3 = acc[m][n][3] + bv4.w;
      if constexpr (GELU_BF16_OUT) {
        bf16x4 o;
        o[0] = (bf16_t)gelu_fast(v0); o[1] = (bf16_t)gelu_fast(v1);
        o[2] = (bf16_t)gelu_fast(v2); o[3] = (bf16_t)gelu_fast(v3);
        *(bf16x4*)(outB + (size_t)row * N + col) = o;
      } else {
        bf16x4 rr = *(const bf16x4*)(resid + (size_t)row * N + col);
        float4 o;
        o.x = v0 + (float)rr[0]; o.y = v1 + (float)rr[1];
        o.z = v2 + (float)rr[2]; o.w = v3 + (float)rr[3];
        *(float4*)(outF + (size_t)row * N + col) = o;
      }
    }
  }
}

extern "C" void kernel_launch(void* const* d_in, const int* in_sizes, int n_in,
                              void* d_out, int out_size, void* d_ws, size_t ws_size,
                              hipStream_t stream) {
  const float* x    = (const float*)d_in[0];
  const float* ln1w = (const float*)d_in[1];
  const float* ln1b = (const float*)d_in[2];
  const float* ln2w = (const float*)d_in[3];
  const float* ln2b = (const float*)d_in[4];
  const float* w1   = (const float*)d_in[5];
  const float* b1   = (const float*)d_in[6];
  const float* w2   = (const float*)d_in[7];
  const float* b2   = (const float*)d_in[8];
  float* out = (float*)d_out;

  // workspace layout (peak < 128 MB, lifetime-checked):
  //  w1b [0,8M)   w2b [8M,16M)                   (all steps)
  //  reT [16M,33M)  imT [33M,50M)                (steps 2-3)
  //  fT  [50M,67M)                               (steps 3-4)
  //  y   [67M,99M)                               (steps 4-5)
  //  xn  [99M,115M)                              (steps 5-7, GEMM2 resid)
  //  hg  [16M,80M)  (reuses reT/imT/fT/y-tail)   (steps 6-7)
  char* ws = (char*)d_ws;
  bf16_t* w1b = (bf16_t*)(ws);
  bf16_t* w2b = (bf16_t*)(ws + (8u  << 20));
  float*  reT = (float*) (ws + (16u << 20));
  float*  imT = (float*) (ws + (33u << 20));
  float*  fT  = (float*) (ws + (50u << 20));
  float*  y   = (float*) (ws + (67u << 20));
  bf16_t* xn  = (bf16_t*)(ws + (99u << 20));
  bf16_t* hg  = (bf16_t*)(ws + (16u << 20));

  // 1. weight transposes + bf16 conversion
  transpose_to_bf16<<<dim3(DFF/32, HD/32), dim3(32, 8), 0, stream>>>(w1, w1b, HD, DFF);
  transpose_to_bf16<<<dim3(HD/32, DFF/32), dim3(32, 8), 0, stream>>>(w2, w2b, DFF, HD);

  // 2. fused FFT along h + transposed truncated store
  fft_h_t<<<NROWS/RPB, 512, 0, stream>>>(x, reT, imT);

  // 3. FFT along s per (h<=512, batch) column; real part out
  fft_s_col<<<dim3(513, 4), 256, 0, stream>>>(reT, imT, fT);

  // 4. untranspose + Hermitian mirror + residual add
  umadd_kernel<<<dim3(HD/32, NROWS/32), dim3(32, 8), 0, stream>>>(fT, x, y);

  // 5. LN1 -> bf16
  layernorm_k<true><<<NROWS, 256, 0, stream>>>(y, ln1w, ln1b, xn, nullptr);

  // 6./7. FFN (1D grids, XCD-swizzled inside the kernel)
  gemm_bf16_kernel<true><<<(DFF/128)*(NROWS/128), 256, 0, stream>>>(
      xn, w1b, b1, nullptr, hg, nullptr, NROWS, DFF, HD, DFF/128);
  gemm_bf16_kernel<false><<<(HD/128)*(NROWS/128), 256, 0, stream>>>(
      hg, w2b, b2, xn, nullptr, out, NROWS, HD, DFF, HD/128);

  // 8. LN2 in place on d_out
  layernorm_k<false><<<NROWS, 256, 0, stream>>>(out, ln2w, ln2b, nullptr, out);
}